// Round 4
// baseline (238.571 us; speedup 1.0000x reference)
//
#include <hip/hip_runtime.h>
#include <math.h>

#define T_TOKENS 16384
#define D_DIM    2048
#define E_EXP    64
#define TOPK     8
#define NS       8                   // K slices (one per block; B-slice = 64 KB LDS)
#define KC       32                  // k per chunk
#define NCH      (D_DIM / NS / KC)   // 8 chunks per slice
#define TTOK     256                 // tokens per block (16 waves x 16)

typedef __attribute__((ext_vector_type(8))) short bf16x8;
typedef __attribute__((ext_vector_type(4))) float f32x4;

__device__ __forceinline__ unsigned short bf16rne(float f) {
  unsigned u = __builtin_bit_cast(unsigned, f);
  unsigned r = u + 0x7fffu + ((u >> 16) & 1u);
  return (unsigned short)(r >> 16);
}
__device__ __forceinline__ float bf16f(unsigned short h) {
  return __builtin_bit_cast(float, (unsigned)h << 16);
}

// ---------------- Kernel 0: pre-convert gate_w to frag-ordered bf16 hi/lo ----
// entry id = ((c*4 + kq)*64 + e): c = k/32 chunk, kq = k-quad, e = expert.
// Entry = 8 bf16 (16 B) = g[e][c*32 + kq*8 .. +7]. Also zeroes counts region.
__global__ __launch_bounds__(256) void convert_g_kernel(
    const float* __restrict__ gw, unsigned short* __restrict__ ph,
    unsigned short* __restrict__ pl, float* __restrict__ counts_zero)
{
  const int id = blockIdx.x * 256 + threadIdx.x;   // 0..16383
  if (blockIdx.x == 0 && threadIdx.x < E_EXP) counts_zero[threadIdx.x] = 0.0f;

  const int e  = id & 63;
  const int kq = (id >> 6) & 3;
  const int c  = id >> 8;
  const float* gp = &gw[(size_t)e * D_DIM + c * 32 + kq * 8];
  float4 v0 = *(const float4*)&gp[0];
  float4 v1 = *(const float4*)&gp[4];
  const float xs[8] = {v0.x, v0.y, v0.z, v0.w, v1.x, v1.y, v1.z, v1.w};
  bf16x8 hi, lo;
  #pragma unroll
  for (int j = 0; j < 8; ++j) {
    unsigned short h = bf16rne(xs[j]);
    hi[j] = (short)h;
    lo[j] = (short)bf16rne(xs[j] - bf16f(h));
  }
  *(bf16x8*)&ph[(size_t)id * 8] = hi;
  *(bf16x8*)&pl[(size_t)id * 8] = lo;
}

// ---------------- Kernel 1: partial logits, B-slice resident in LDS ----------
// grid (64 tiles, 8 slices), 1024 thr = 16 waves; wave w owns tokens
// [tile*256 + w*16, +16), all waves on slice ks = blockIdx.y (k in [ks*256,+256)).
// R3 diagnosis: 80% of VMEM insts were re-reads of the same 32 KB of B per
// chunk-phase -> L2 hot-line serialization (905 GB/s, all pipes <15% busy).
// Here the slice's B (hi 32 KB + lo 32 KB, frag-ordered = linear copy of
// ph/pl[ks*16384..+16384) shorts) is staged to LDS ONCE, then the K-loop is
// barrier-free: A from global (2 insts/chunk/wave), B via ds_read_b128
// (uniform-8 lanes per 16B slot -> conflict-free; LDS pipe runs parallel to
// VMEM). Numerics identical: same bf16 hi/lo split, 12 MFMA/chunk, same
// A/B/C fragment mappings as the validated kernels.
__global__ __launch_bounds__(1024, 4) void moe_logits_kernel(
    const float* __restrict__ x, const unsigned short* __restrict__ ph,
    const unsigned short* __restrict__ pl, float* __restrict__ part)
{
  __shared__ unsigned short bsm[32768];   // 64 KB: [0,16384) hi, [16384,32768) lo

  const int tid  = threadIdx.x;
  const int wave = tid >> 6;
  const int lane = tid & 63;
  const int l15  = lane & 15;
  const int quad = lane >> 4;
  const int ks   = blockIdx.y;
  const int k0   = ks * (D_DIM / NS);
  const int tokw = blockIdx.x * TTOK + wave * 16;

  // ---- stage B slice into LDS (linear copy; 1024 thr x 16 B x 4 rounds) ----
  {
    const unsigned short* hsrc = ph + (size_t)ks * (NCH * 2048);
    const unsigned short* lsrc = pl + (size_t)ks * (NCH * 2048);
    bf16x8 v0 = *(const bf16x8*)&hsrc[tid * 8];
    bf16x8 v1 = *(const bf16x8*)&hsrc[8192 + tid * 8];
    bf16x8 v2 = *(const bf16x8*)&lsrc[tid * 8];
    bf16x8 v3 = *(const bf16x8*)&lsrc[8192 + tid * 8];
    *(bf16x8*)&bsm[tid * 8]          = v0;
    *(bf16x8*)&bsm[8192  + tid * 8]  = v1;
    *(bf16x8*)&bsm[16384 + tid * 8]  = v2;
    *(bf16x8*)&bsm[24576 + tid * 8]  = v3;
  }

  // A source: this lane's token row, this quad's 32-byte k-segment
  const float* xg = &x[(size_t)(tokw + l15) * D_DIM + k0 + quad * 8];

  f32x4 acc[4];
  #pragma unroll
  for (int et = 0; et < 4; ++et) acc[et] = (f32x4){0.f, 0.f, 0.f, 0.f};

  // ---- prologue: load chunk 0's A (overlaps the staging barrier) ----
  float4 p0 = *(const float4*)xg;
  float4 p1 = *(const float4*)(xg + 4);

  __syncthreads();   // B slice resident; no barriers after this

  // per-lane B base inside LDS (shorts): c*2048 + quad*512 + l15*8 (+ et*128)
  const unsigned short* bh_l = &bsm[quad * 512 + l15 * 8];
  const unsigned short* bl_l = bh_l + 16384;

  #pragma unroll 1
  for (int c = 0; c < NCH; ++c) {
    // ---- all 8 B-frags for this chunk from LDS (conflict-free b128) ----
    const unsigned short* ch = bh_l + c * 2048;
    const unsigned short* cl = bl_l + c * 2048;
    bf16x8 bh[4], bl[4];
    #pragma unroll
    for (int et = 0; et < 4; ++et) {
      bh[et] = *(const bf16x8*)&ch[et * 128];
      bl[et] = *(const bf16x8*)&cl[et * 128];
    }

    // ---- prefetch next chunk's A (in flight during convert + MFMA) ----
    float4 n0 = {0.f, 0.f, 0.f, 0.f}, n1 = {0.f, 0.f, 0.f, 0.f};
    if (c + 1 < NCH) {
      n0 = *(const float4*)(xg + (c + 1) * KC);
      n1 = *(const float4*)(xg + (c + 1) * KC + 4);
    }

    // ---- split current A chunk to hi/lo bf16 (register-only) ----
    const float xs[8] = {p0.x, p0.y, p0.z, p0.w, p1.x, p1.y, p1.z, p1.w};
    bf16x8 ah, al;
    #pragma unroll
    for (int j = 0; j < 8; ++j) {
      unsigned short h = bf16rne(xs[j]);
      ah[j] = (short)h;
      al[j] = (short)bf16rne(xs[j] - bf16f(h));
    }

    // ---- 12 MFMAs ----
    #pragma unroll
    for (int et = 0; et < 4; ++et) {
      acc[et] = __builtin_amdgcn_mfma_f32_16x16x32_bf16(ah, bh[et], acc[et], 0, 0, 0);
      acc[et] = __builtin_amdgcn_mfma_f32_16x16x32_bf16(al, bh[et], acc[et], 0, 0, 0);
      acc[et] = __builtin_amdgcn_mfma_f32_16x16x32_bf16(ah, bl[et], acc[et], 0, 0, 0);
    }

    p0 = n0; p1 = n1;   // dead on last iteration
  }

  // ---- store partials: D row(m) = quad*4 + r (token), col(n) = l15 (expert) ----
  #pragma unroll
  for (int et = 0; et < 4; ++et) {
    #pragma unroll
    for (int r = 0; r < 4; ++r) {
      const size_t t = (size_t)tokw + quad * 4 + r;
      part[((size_t)ks * T_TOKENS + t) * E_EXP + et * 16 + l15] = acc[et][r];
    }
  }
}

// ---------------- Kernel 2: reduce + bias, top-8, softmax, counts ----------------
__global__ __launch_bounds__(64) void topk_kernel(
    const float* __restrict__ part, const float* __restrict__ bias,
    float* __restrict__ out)
{
  __shared__ unsigned hist[E_EXP];
  const int tid = threadIdx.x;            // 0..63
  const int t = blockIdx.x * 64 + tid;
  hist[tid] = 0;
  __syncthreads();

  float l[E_EXP];
  #pragma unroll
  for (int j = 0; j < E_EXP / 4; ++j) {
    float4 b = *(const float4*)&bias[j * 4];
    l[4*j] = b.x; l[4*j+1] = b.y; l[4*j+2] = b.z; l[4*j+3] = b.w;
  }
  #pragma unroll 2
  for (int ks = 0; ks < NS; ++ks) {
    const float4* p = (const float4*)&part[((size_t)ks * T_TOKENS + t) * E_EXP];
    #pragma unroll
    for (int j = 0; j < E_EXP / 4; ++j) {
      float4 v = p[j];
      l[4*j] += v.x; l[4*j+1] += v.y; l[4*j+2] += v.z; l[4*j+3] += v.w;
    }
  }

  float tv[TOPK]; int tix[TOPK];
  unsigned long long used = 0ull;
  #pragma unroll
  for (int k = 0; k < TOPK; ++k) {
    float best = -INFINITY; int bi = 0;
    #pragma unroll
    for (int j = 0; j < E_EXP; ++j) {
      bool ok = (((used >> j) & 1ull) == 0ull) && (l[j] > best);  // strict >: lowest index wins ties
      best = ok ? l[j] : best;
      bi   = ok ? j : bi;
    }
    tv[k] = best; tix[k] = bi;
    used |= (1ull << bi);
  }

  float m = tv[0], s = 0.0f, w[TOPK];
  #pragma unroll
  for (int k = 0; k < TOPK; ++k) { w[k] = expf(tv[k] - m); s += w[k]; }
  float inv = 1.0f / s;

  #pragma unroll
  for (int k = 0; k < TOPK; ++k) {
    out[(size_t)t * TOPK + k] = (float)tix[k];                        // indices as fp32
    out[(size_t)T_TOKENS * TOPK + (size_t)t * TOPK + k] = w[k] * inv; // weights
  }

  #pragma unroll
  for (int k = 0; k < TOPK; ++k) atomicAdd(&hist[tix[k]], 1u);
  __syncthreads();
  atomicAdd(&out[2 * (size_t)T_TOKENS * TOPK + tid], (float)hist[tid]);
}

extern "C" void kernel_launch(void* const* d_in, const int* in_sizes, int n_in,
                              void* d_out, int out_size, void* d_ws, size_t ws_size,
                              hipStream_t stream) {
  const float* x    = (const float*)d_in[0];
  const float* gw   = (const float*)d_in[1];
  const float* bias = (const float*)d_in[2];
  float* out  = (float*)d_out;

  // ws layout: part (NS*4 MB = 32 MB) | ph (256 KB) | pl (256 KB)
  float* part = (float*)d_ws;
  const size_t part_elems = (size_t)NS * T_TOKENS * E_EXP;
  unsigned short* ph = (unsigned short*)((char*)d_ws + part_elems * sizeof(float));
  unsigned short* pl = ph + (size_t)E_EXP * D_DIM;

  convert_g_kernel<<<dim3(E_EXP * D_DIM / 8 / 256), dim3(256), 0, stream>>>(
      gw, ph, pl, out + 2 * (size_t)T_TOKENS * TOPK);
  moe_logits_kernel<<<dim3(T_TOKENS / TTOK, NS), dim3(1024), 0, stream>>>(
      x, ph, pl, part);
  topk_kernel<<<dim3(T_TOKENS / 64), dim3(64), 0, stream>>>(part, bias, out);
}

// Round 5
// 214.868 us; speedup vs baseline: 1.1103x; 1.1103x over previous
//
#include <hip/hip_runtime.h>
#include <math.h>

#define T_TOKENS 16384
#define D_DIM    2048
#define E_EXP    64
#define TOPK     8
#define NS       4                   // K slices (across waves within a block)
#define KC       32                  // k per chunk (phase)
#define NCH      (D_DIM / NS / KC)   // 16 phases
#define TT       32                  // tokens per block (2 blocks/CU)
#define TOKP     36                  // token stride in epilogue slab (16B-aligned rows)

typedef __attribute__((ext_vector_type(8))) short bf16x8;
typedef __attribute__((ext_vector_type(4))) float f32x4;

__device__ __forceinline__ unsigned short bf16rne(float f) {
  unsigned u = __builtin_bit_cast(unsigned, f);
  unsigned r = u + 0x7fffu + ((u >> 16) & 1u);
  return (unsigned short)(r >> 16);
}
__device__ __forceinline__ float bf16f(unsigned short h) {
  return __builtin_bit_cast(float, (unsigned)h << 16);
}

// ---------------- Kernel 0: pre-convert gate_w to frag-ordered bf16 hi/lo ----
// entry id = ((c*4 + kq)*64 + e): c = k/32 chunk, kq = k-quad, e = expert.
// Entry = 8 bf16 (16 B) = g[e][c*32 + kq*8 .. +7]. Also zeroes counts region.
__global__ __launch_bounds__(256) void convert_g_kernel(
    const float* __restrict__ gw, unsigned short* __restrict__ ph,
    unsigned short* __restrict__ pl, float* __restrict__ counts_zero)
{
  const int id = blockIdx.x * 256 + threadIdx.x;   // 0..16383
  if (blockIdx.x == 0 && threadIdx.x < E_EXP) counts_zero[threadIdx.x] = 0.0f;

  const int e  = id & 63;
  const int kq = (id >> 6) & 3;
  const int c  = id >> 8;
  const float* gp = &gw[(size_t)e * D_DIM + c * 32 + kq * 8];
  float4 v0 = *(const float4*)&gp[0];
  float4 v1 = *(const float4*)&gp[4];
  const float xs[8] = {v0.x, v0.y, v0.z, v0.w, v1.x, v1.y, v1.z, v1.w};
  bf16x8 hi, lo;
  #pragma unroll
  for (int j = 0; j < 8; ++j) {
    unsigned short h = bf16rne(xs[j]);
    hi[j] = (short)h;
    lo[j] = (short)bf16rne(xs[j] - bf16f(h));
  }
  *(bf16x8*)&ph[(size_t)id * 8] = hi;
  *(bf16x8*)&pl[(size_t)id * 8] = lo;
}

// ---------------- Kernel 1 (fused): logits + reduce + top-8 + counts ----------
// R3+R4 combination: R3's fused geometry (512 blocks x 512 thr = 8 waves =
// 2 token-groups x 4 K-slices, 2 blocks/CU, validated epilogue) with R4's
// LDS-resident B (fixes the L2 hot-line serialization that pinned the K-loop
// at 905 GB/s / 78 us). Per 32-k phase, the block stages the 4 slices' B chunk
// (hi+lo = 32 KB) into one of two LDS buffers; single barrier per phase.
// LDS frag bytes == global frag bytes (offset wsl*4096+hl*2048+quad*512+
// (et*16+l15)*8 maps 1:1 to ph/pl[(wsl*16+c)*2048 + same]), so MFMA operands
// and all numerics are bit-identical to the passing versions. Depth-2 A
// register prefetch keeps the x stream outstanding across barriers (staging
// loads are issued earlier, so the compiler's counted vmcnt drains them
// without draining A). B double-buffer (64 KB) is aliased as the epilogue
// slab (36.9 KB) after the final barrier.
__global__ __launch_bounds__(512, 4) void moe_fused_kernel(
    const float* __restrict__ x, const unsigned short* __restrict__ ph,
    const unsigned short* __restrict__ pl, const float* __restrict__ bias,
    float* __restrict__ out)
{
  __shared__ unsigned short bsm[2][16384];   // 2 x 32 KB B buffers; epilogue slab alias
  __shared__ unsigned hist[E_EXP];

  const int tid  = threadIdx.x;
  const int wave = tid >> 6;
  const int lane = tid & 63;
  const int l15  = lane & 15;
  const int quad = lane >> 4;
  const int wg   = wave & 1;          // token group (0..1)
  const int wsl  = wave >> 1;         // K slice (0..3)
  const int k0   = wsl * (D_DIM / NS);
  const int tokw = blockIdx.x * TT + wg * 16;

  // staging map: thread covers 16 B of each slice's chunk; hi for tid<256, lo else
  const int st_hl  = tid >> 8;               // 0 = hi(ph), 1 = lo(pl)
  const int st_off = (tid & 255) * 8;        // shorts within a 4 KB chunk segment
  const unsigned short* st_base = st_hl ? pl : ph;

#define STAGE_LOAD(c, r0, r1, r2, r3)                                   \
  {                                                                     \
    r0 = *(const bf16x8*)&st_base[((size_t)(0 * NCH + (c))) * 2048 + st_off]; \
    r1 = *(const bf16x8*)&st_base[((size_t)(1 * NCH + (c))) * 2048 + st_off]; \
    r2 = *(const bf16x8*)&st_base[((size_t)(2 * NCH + (c))) * 2048 + st_off]; \
    r3 = *(const bf16x8*)&st_base[((size_t)(3 * NCH + (c))) * 2048 + st_off]; \
  }
#define STAGE_WRITE(buf, r0, r1, r2, r3)                                \
  {                                                                     \
    unsigned short* d = &bsm[buf][st_hl * 2048 + st_off];               \
    *(bf16x8*)&d[0]     = r0;                                           \
    *(bf16x8*)&d[4096]  = r1;                                           \
    *(bf16x8*)&d[8192]  = r2;                                           \
    *(bf16x8*)&d[12288] = r3;                                           \
  }

  // A source: this lane's token row, this quad's 32-byte k-segment
  const float* xg = &x[(size_t)(tokw + l15) * D_DIM + k0 + quad * 8];

  f32x4 acc[4];
  #pragma unroll
  for (int et = 0; et < 4; ++et) acc[et] = (f32x4){0.f, 0.f, 0.f, 0.f};

  // ---- prologue: stage phase 0's B; load A(0) and A(1) ----
  {
    bf16x8 s0, s1, s2, s3;
    STAGE_LOAD(0, s0, s1, s2, s3);
    STAGE_WRITE(0, s0, s1, s2, s3);
  }
  float4 aA0 = *(const float4*)xg;            // A(0)
  float4 aA1 = *(const float4*)(xg + 4);
  float4 aB0 = *(const float4*)(xg + KC);     // A(1)
  float4 aB1 = *(const float4*)(xg + KC + 4);
  __syncthreads();   // buffer 0 resident

  #pragma unroll 1
  for (int c = 0; c < NCH; ++c) {
    const int cur = c & 1;

    // ---- issue staging loads for phase c+1 (drained before barrier; A stays in flight) ----
    bf16x8 t0, t1, t2, t3;
    if (c + 1 < NCH) STAGE_LOAD(c + 1, t0, t1, t2, t3);

    // ---- all 8 B-frags for this phase from LDS (conflict-free b128) ----
    const unsigned short* bb = &bsm[cur][wsl * 4096 + quad * 512 + l15 * 8];
    bf16x8 bh[4], bl[4];
    #pragma unroll
    for (int et = 0; et < 4; ++et) {
      bh[et] = *(const bf16x8*)&bb[et * 128];
      bl[et] = *(const bf16x8*)&bb[2048 + et * 128];
    }

    // ---- depth-2 A prefetch: issue A(c+2) ----
    float4 n0 = {0.f, 0.f, 0.f, 0.f}, n1 = {0.f, 0.f, 0.f, 0.f};
    if (c + 2 < NCH) {
      n0 = *(const float4*)(xg + (c + 2) * KC);
      n1 = *(const float4*)(xg + (c + 2) * KC + 4);
    }

    // ---- split current A chunk to hi/lo bf16 (register-only) ----
    const float xs[8] = {aA0.x, aA0.y, aA0.z, aA0.w, aA1.x, aA1.y, aA1.z, aA1.w};
    bf16x8 ah, al;
    #pragma unroll
    for (int j = 0; j < 8; ++j) {
      unsigned short h = bf16rne(xs[j]);
      ah[j] = (short)h;
      al[j] = (short)bf16rne(xs[j] - bf16f(h));
    }

    // ---- 12 MFMAs ----
    #pragma unroll
    for (int et = 0; et < 4; ++et) {
      acc[et] = __builtin_amdgcn_mfma_f32_16x16x32_bf16(ah, bh[et], acc[et], 0, 0, 0);
      acc[et] = __builtin_amdgcn_mfma_f32_16x16x32_bf16(al, bh[et], acc[et], 0, 0, 0);
      acc[et] = __builtin_amdgcn_mfma_f32_16x16x32_bf16(ah, bl[et], acc[et], 0, 0, 0);
    }

    // ---- write staged B for phase c+1 into the other buffer ----
    if (c + 1 < NCH) STAGE_WRITE(cur ^ 1, t0, t1, t2, t3);
    __syncthreads();   // phase c reads done everywhere; c+1 buffer resident

    aA0 = aB0; aA1 = aB1; aB0 = n0; aB1 = n1;   // rotate A pipeline
  }

  // ---- epilogue (validated R3 structure; slab aliases the B buffers) ----
  float* slab = (float*)&bsm[0][0];   // NS*E_EXP*TOKP floats = 36864 B <= 64 KB

  // acc -> LDS, expert-major: slab[wsl][e = et*16+l15][tok = wg*16+quad*4+r]
  #pragma unroll
  for (int et = 0; et < 4; ++et) {
    *(f32x4*)&slab[((size_t)(wsl * E_EXP + et * 16 + l15)) * TOKP + wg * 16 + quad * 4] = acc[et];
  }
  if (tid < E_EXP) hist[tid] = 0;
  __syncthreads();

  // reduce 4 slices + bias into slice 0 (512 thr x f32x4 = 64 experts x 32 tokens).
  // Summation order identical to previous passing versions: bias, +s0..+s3.
  {
    const int e  = tid >> 3;          // 0..63
    const int t4 = (tid & 7) * 4;     // 0..28
    f32x4 s0 = *(const f32x4*)&slab[(size_t)(0 * E_EXP + e) * TOKP + t4];
    f32x4 s1 = *(const f32x4*)&slab[(size_t)(1 * E_EXP + e) * TOKP + t4];
    f32x4 s2 = *(const f32x4*)&slab[(size_t)(2 * E_EXP + e) * TOKP + t4];
    f32x4 s3 = *(const f32x4*)&slab[(size_t)(3 * E_EXP + e) * TOKP + t4];
    const float b = bias[e];
    f32x4 v;
    #pragma unroll
    for (int j = 0; j < 4; ++j) v[j] = (((b + s0[j]) + s1[j]) + s2[j]) + s3[j];
    *(f32x4*)&slab[(size_t)(0 * E_EXP + e) * TOKP + t4] = v;
  }
  __syncthreads();

  if (tid >= 64) return;   // waves 1..7 done; wave 0 finishes the 32 tokens

  if (tid < TT) {
    const int t = tid;
    float l[E_EXP];
    #pragma unroll
    for (int j = 0; j < E_EXP; ++j) l[j] = slab[(size_t)j * TOKP + t];

    float tv[TOPK]; int tix[TOPK];
    unsigned long long used = 0ull;
    #pragma unroll
    for (int k = 0; k < TOPK; ++k) {
      float best = -INFINITY; int bi = 0;
      #pragma unroll
      for (int j = 0; j < E_EXP; ++j) {
        bool ok = (((used >> j) & 1ull) == 0ull) && (l[j] > best);  // strict >: lowest index wins ties
        best = ok ? l[j] : best;
        bi   = ok ? j : bi;
      }
      tv[k] = best; tix[k] = bi;
      used |= (1ull << bi);
    }

    float m = tv[0], s = 0.0f, w[TOPK];
    #pragma unroll
    for (int k = 0; k < TOPK; ++k) { w[k] = expf(tv[k] - m); s += w[k]; }
    float inv = 1.0f / s;

    const size_t gt = (size_t)blockIdx.x * TT + t;
    #pragma unroll
    for (int k = 0; k < TOPK; ++k) {
      out[gt * TOPK + k] = (float)tix[k];                                // indices as fp32
      out[(size_t)T_TOKENS * TOPK + gt * TOPK + k] = w[k] * inv;         // weights
    }

    #pragma unroll
    for (int k = 0; k < TOPK; ++k) atomicAdd(&hist[tix[k]], 1u);
  }
  __threadfence_block();   // order wave-0's LDS atomics before its reads
  atomicAdd(&out[2 * (size_t)T_TOKENS * TOPK + tid], (float)hist[tid]);
}

extern "C" void kernel_launch(void* const* d_in, const int* in_sizes, int n_in,
                              void* d_out, int out_size, void* d_ws, size_t ws_size,
                              hipStream_t stream) {
  const float* x    = (const float*)d_in[0];
  const float* gw   = (const float*)d_in[1];
  const float* bias = (const float*)d_in[2];
  float* out  = (float*)d_out;

  // ws layout: ph (256 KB) | pl (256 KB)
  unsigned short* ph = (unsigned short*)d_ws;
  unsigned short* pl = ph + (size_t)E_EXP * D_DIM;

  convert_g_kernel<<<dim3(E_EXP * D_DIM / 8 / 256), dim3(256), 0, stream>>>(
      gw, ph, pl, out + 2 * (size_t)T_TOKENS * TOPK);
  moe_fused_kernel<<<dim3(T_TOKENS / TT), dim3(512), 0, stream>>>(
      x, ph, pl, bias, out);
}